// Round 9
// baseline (1658.123 us; speedup 1.0000x reference)
//
#include <hip/hip_runtime.h>
#include <hip/hip_bf16.h>

#define NNODES 10000
#define NEDGE_IN 320000
#define ETOT (NEDGE_IN + NNODES)
#define FDIM 256
#define NT 79  // 128-tiles covering 10000

typedef float floatx4 __attribute__((ext_vector_type(4)));
typedef float floatx2 __attribute__((ext_vector_type(2)));
typedef __bf16 bf16x8 __attribute__((ext_vector_type(8)));

__device__ __forceinline__ float bf2f(unsigned short u) {
  return __uint_as_float((unsigned)u << 16);
}

// ---------------- merged preprocessing: split | prep_bt | prep_wa | count_deg ----------------
// All four branches read only external inputs (x, W, a, ei) -> no inter-branch deps.
// Block ranges: [0,10000) split, [10000,11024) bt, [11024,12048) wa, [12048,13338) count.
__global__ __launch_bounds__(256) void preproc_kernel(
    const float* __restrict__ x, const int* __restrict__ ei,
    const float* __restrict__ W0, const float* __restrict__ W1,
    const float* __restrict__ W2, const float* __restrict__ W3,
    const float* __restrict__ as0, const float* __restrict__ as1,
    const float* __restrict__ as2, const float* __restrict__ as3,
    const float* __restrict__ ad0, const float* __restrict__ ad1,
    const float* __restrict__ ad2, const float* __restrict__ ad3,
    unsigned short* __restrict__ shi, unsigned short* __restrict__ slo,
    unsigned short* __restrict__ btHi, unsigned short* __restrict__ btLo,
    float* __restrict__ Was, float* __restrict__ Wad, int* __restrict__ counts) {
  __shared__ float smem[32 * 33];
  int b = blockIdx.x, t = threadIdx.x;
  if (b < 10000) {
    // split fp32 -> hi/lo bf16
    int i = b * 256 + t;  // 10000*256 exactly
    float v = x[i];
    unsigned u = __float_as_uint(v);
    float r = v - __uint_as_float(u & 0xffff0000u);
    shi[i] = (unsigned short)(u >> 16);
    slo[i] = (unsigned short)(__float_as_uint(r) >> 16);
  } else if (b < 11024) {
    // BT prep: BT_l[f, h*256+k] = 0.25*W_l[k, h*256+f], split hi/lo
    int idx = b - 10000;
    int fx = idx & 7, ky = (idx >> 3) & 7, zi = idx >> 6;
    int h = zi & 3, lay = zi >> 2;
    const float* W = (lay == 0) ? W0 : (lay == 1) ? W1 : (lay == 2) ? W2 : W3;
    size_t lofs = (size_t)lay * 262144;
    float(*tile)[33] = (float(*)[33])smem;
    int tx = t & 31, ty = t >> 5;
    int f0 = fx * 32, k0 = ky * 32;
#pragma unroll
    for (int i = 0; i < 4; i++) {
      int kr = ty + 8 * i;
      tile[kr][tx] = W[(size_t)(k0 + kr) * 1024 + h * 256 + f0 + tx];
    }
    __syncthreads();
#pragma unroll
    for (int i = 0; i < 4; i++) {
      int fr = ty + 8 * i;
      float v = 0.25f * tile[tx][fr];
      unsigned u = __float_as_uint(v);
      float r = v - __uint_as_float(u & 0xffff0000u);
      size_t o = lofs + (size_t)(f0 + fr) * 1024 + h * 256 + k0 + tx;
      btHi[o] = (unsigned short)(u >> 16);
      btLo[o] = (unsigned short)(__float_as_uint(r) >> 16);
    }
  } else if (b < 12048) {
    // Wa prep: Was_l/Wad_l[k,h] = sum_f W_l[k,h*256+f] * a_l[h,f]
    int idx = b - 11024;
    int k = idx & 255, lay = idx >> 8;
    const float* W = (lay == 0) ? W0 : (lay == 1) ? W1 : (lay == 2) ? W2 : W3;
    const float* a_src = (lay == 0) ? as0 : (lay == 1) ? as1 : (lay == 2) ? as2 : as3;
    const float* a_dst = (lay == 0) ? ad0 : (lay == 1) ? ad1 : (lay == 2) ? ad2 : ad3;
    float ps[4], pd[4];
#pragma unroll
    for (int hd = 0; hd < 4; hd++) {
      float w = W[(size_t)k * 1024 + hd * 256 + t];
      ps[hd] = w * a_src[hd * 256 + t];
      pd[hd] = w * a_dst[hd * 256 + t];
    }
    float(*red)[4] = (float(*)[4])smem;
    int lane = t & 63, wv = t >> 6;
#pragma unroll
    for (int q = 0; q < 8; q++) {
      float v = (q < 4) ? ps[q] : pd[q - 4];
#pragma unroll
      for (int off = 32; off > 0; off >>= 1) v += __shfl_down(v, off, 64);
      if (lane == 0) red[q][wv] = v;
    }
    __syncthreads();
    if (t < 8) {
      float v = red[t][0] + red[t][1] + red[t][2] + red[t][3];
      if (t < 4) Was[lay * 1024 + k * 4 + t] = v;
      else Wad[lay * 1024 + k * 4 + (t - 4)] = v;
    }
  } else {
    // count_deg
    int e = (b - 12048) * 256 + t;
    if (e < ETOT) {
      int d = (e < NEDGE_IN) ? ei[NEDGE_IN + e] : (e - NEDGE_IN);
      atomicAdd(&counts[d], 1);
    }
  }
}

__global__ __launch_bounds__(256) void scan_kernel(const int* __restrict__ counts,
                                                   int* __restrict__ row_ptr,
                                                   int* __restrict__ fill) {
  int t = threadIdx.x;
  const int CH = 40;
  int base = t * CH;
  int local[CH];
  int sum = 0;
#pragma unroll
  for (int i = 0; i < CH; i++) {
    int idx = base + i;
    int v = (idx < NNODES) ? counts[idx] : 0;
    local[i] = sum;
    sum += v;
  }
  __shared__ int ssum[256];
  ssum[t] = sum;
  __syncthreads();
  for (int off = 1; off < 256; off <<= 1) {
    int add = (t >= off) ? ssum[t - off] : 0;
    __syncthreads();
    ssum[t] += add;
    __syncthreads();
  }
  int excl = ssum[t] - sum;
#pragma unroll
  for (int i = 0; i < CH; i++) {
    int idx = base + i;
    if (idx < NNODES) {
      int v = excl + local[i];
      row_ptr[idx] = v;
      fill[idx] = v;
    }
  }
  if (t == 255) row_ptr[NNODES] = ssum[255];
}

__global__ void scatter_kernel(const int* __restrict__ ei, int* __restrict__ fill,
                               int* __restrict__ col_idx) {
  int e = blockIdx.x * blockDim.x + threadIdx.x;
  if (e >= ETOT) return;
  int s, d;
  if (e < NEDGE_IN) { s = ei[e]; d = ei[NEDGE_IN + e]; } else { s = d = e - NEDGE_IN; }
  int pos = atomicAdd(&fill[d], 1);
  col_idx[pos] = s;
}

// ---------------- al_s/al_d[n,h] = X[n,:] @ Was/Wad  (8 threads/node, 3-step DPP reduce) ----------------
__global__ __launch_bounds__(256) void al_kernel(const unsigned short* __restrict__ xhi,
                                                 const unsigned short* __restrict__ xlo,
                                                 const float* __restrict__ Was,
                                                 const float* __restrict__ Wad,
                                                 float* __restrict__ al_s,
                                                 float* __restrict__ al_d) {
  int t = threadIdx.x;
  int kslot = t & 7;   // 8 threads per node, contiguous 32-elem k-slices
  int nslot = t >> 3;  // 32 nodes per block
  int node = blockIdx.x * 32 + nslot;
  int nc = node < NNODES ? node : NNODES - 1;
  const unsigned short* rh = xhi + (size_t)nc * 256;
  const unsigned short* rl = xlo + (size_t)nc * 256;
  float ps[4] = {0.f, 0.f, 0.f, 0.f}, pd[4] = {0.f, 0.f, 0.f, 0.f};
#pragma unroll
  for (int j = 0; j < 8; j++) {
    int k0 = j * 32 + kslot * 4;
    ushort4 h4 = *reinterpret_cast<const ushort4*>(rh + k0);
    ushort4 l4 = *reinterpret_cast<const ushort4*>(rl + k0);
    float xv[4] = {bf2f(h4.x) + bf2f(l4.x), bf2f(h4.y) + bf2f(l4.y),
                   bf2f(h4.z) + bf2f(l4.z), bf2f(h4.w) + bf2f(l4.w)};
#pragma unroll
    for (int m = 0; m < 4; m++) {
      float4 ws = *reinterpret_cast<const float4*>(Was + (k0 + m) * 4);
      float4 wd = *reinterpret_cast<const float4*>(Wad + (k0 + m) * 4);
      ps[0] += xv[m] * ws.x; ps[1] += xv[m] * ws.y; ps[2] += xv[m] * ws.z; ps[3] += xv[m] * ws.w;
      pd[0] += xv[m] * wd.x; pd[1] += xv[m] * wd.y; pd[2] += xv[m] * wd.z; pd[3] += xv[m] * wd.w;
    }
  }
#pragma unroll
  for (int d = 4; d > 0; d >>= 1) {
#pragma unroll
    for (int q = 0; q < 4; q++) {
      ps[q] += __shfl_down(ps[q], d, 64);
      pd[q] += __shfl_down(pd[q], d, 64);
    }
  }
  if (kslot == 0 && node < NNODES) {
    *reinterpret_cast<float4*>(al_s + node * 4) = make_float4(ps[0], ps[1], ps[2], ps[3]);
    *reinterpret_cast<float4*>(al_d + node * 4) = make_float4(pd[0], pd[1], pd[2], pd[3]);
  }
}

// ---------------- gather: 2 waves per node (feature-split), packed-f32 inner loop ----------------
// wave w: node = blk*2 + (w>>1), feature half = w&1 (128 features each, lane*2 within half).
// Per edge per lane: 1x4B coalesced load, 2 unpack, 4 pk_fma, 2 LDS reads (~11 instrs, was ~23).
// esum computed redundantly by both waves of a node -> no cross-wave sync needed.
// Accumulation order per feature unchanged -> bit-identical output vs prior version.
#define ACCP2(ux, ev)                                                              \
  {                                                                                \
    floatx2 _f = {__uint_as_float(ux << 16), __uint_as_float(ux & 0xffff0000u)};   \
    acc2[0] += _f * (floatx2){ev.x, ev.x};                                         \
    acc2[1] += _f * (floatx2){ev.y, ev.y};                                         \
    acc2[2] += _f * (floatx2){ev.z, ev.z};                                         \
    acc2[3] += _f * (floatx2){ev.w, ev.w};                                         \
  }

__global__ __launch_bounds__(256) void gat_gather_kernel(
    const unsigned short* __restrict__ xhi, const float* __restrict__ al_s,
    const float* __restrict__ al_d, const int* __restrict__ row_ptr,
    const int* __restrict__ col_idx,
    unsigned short* __restrict__ aggHi, unsigned short* __restrict__ aggLo, int rep) {
  __shared__ int sS[4][64];
  __shared__ float4 sE[4][64];
  int t = threadIdx.x;
  int lane = t & 63, wv = t >> 6;
  int n = blockIdx.x * 2 + (wv >> 1);
  int fhalf = wv & 1;
  int start = row_ptr[n], end = row_ptr[n + 1];
  float4 ald4 = *reinterpret_cast<const float4*>(al_d + n * 4);
  float ald[4] = {ald4.x, ald4.y, ald4.z, ald4.w};
  const unsigned short* xl = xhi + fhalf * 128 + lane * 2;

#pragma unroll 1
  for (int rp = 0; rp < rep; rp++) {
    floatx2 acc2[4];
#pragma unroll
    for (int h = 0; h < 4; h++) acc2[h] = (floatx2){0.f, 0.f};
    float esum[4] = {0.f, 0.f, 0.f, 0.f};

    for (int c = start; c < end; c += 64) {
      int nch = min(64, end - c);
      int s = 0;
      float ex[4] = {0.f, 0.f, 0.f, 0.f};
      if (lane < nch) {
        s = col_idx[c + lane];
        float4 as4 = *reinterpret_cast<const float4*>(al_s + s * 4);
        float lv[4] = {as4.x + ald[0], as4.y + ald[1], as4.z + ald[2], as4.w + ald[3]};
#pragma unroll
        for (int h = 0; h < 4; h++) {
          float l = lv[h];
          l = (l > 0.f) ? l : 0.2f * l;
          l = fminf(l, 60.f);
          float e = __expf(l);
          ex[h] = e;
          esum[h] += e;
        }
      }
      sS[wv][lane] = s;
      sE[wv][lane] = make_float4(ex[0], ex[1], ex[2], ex[3]);
      __asm__ __volatile__("" ::: "memory");  // per-wave LDS ops are in-order; pin compiler order
      int i = 0;
      for (; i + 4 <= nch; i += 4) {
        int s0 = sS[wv][i], s1 = sS[wv][i + 1], s2 = sS[wv][i + 2], s3 = sS[wv][i + 3];
        float4 e0 = sE[wv][i], e1 = sE[wv][i + 1], e2 = sE[wv][i + 2], e3 = sE[wv][i + 3];
        unsigned x0 = *reinterpret_cast<const unsigned*>(xl + (size_t)s0 * 256);
        unsigned x1 = *reinterpret_cast<const unsigned*>(xl + (size_t)s1 * 256);
        unsigned x2 = *reinterpret_cast<const unsigned*>(xl + (size_t)s2 * 256);
        unsigned x3 = *reinterpret_cast<const unsigned*>(xl + (size_t)s3 * 256);
        ACCP2(x0, e0);
        ACCP2(x1, e1);
        ACCP2(x2, e2);
        ACCP2(x3, e3);
      }
      for (; i < nch; i++) {
        int s0 = sS[wv][i];
        float4 e0 = sE[wv][i];
        unsigned x0 = *reinterpret_cast<const unsigned*>(xl + (size_t)s0 * 256);
        ACCP2(x0, e0);
      }
      __asm__ __volatile__("" ::: "memory");
    }

#pragma unroll
    for (int h = 0; h < 4; h++) {
#pragma unroll
      for (int m = 32; m > 0; m >>= 1) esum[h] += __shfl_xor(esum[h], m, 64);
    }

#pragma unroll
    for (int h = 0; h < 4; h++) {
      float inv = 1.f / (esum[h] + 1e-16f);
      float v0 = acc2[h].x * inv, v1 = acc2[h].y * inv;
      unsigned u0 = __float_as_uint(v0);
      float r0 = v0 - __uint_as_float(u0 & 0xffff0000u);
      unsigned u1 = __float_as_uint(v1);
      float r1 = v1 - __uint_as_float(u1 & 0xffff0000u);
      ushort2 hv, lv;
      hv.x = (unsigned short)(u0 >> 16);
      hv.y = (unsigned short)(u1 >> 16);
      lv.x = (unsigned short)(__float_as_uint(r0) >> 16);
      lv.y = (unsigned short)(__float_as_uint(r1) >> 16);
      size_t o = (size_t)n * 1024 + h * 256 + fhalf * 128 + lane * 2;
      *reinterpret_cast<ushort2*>(aggHi + o) = hv;
      *reinterpret_cast<ushort2*>(aggLo + o) = lv;
    }
  }
}

// ---------------- MFMA GEMM: out[N,256] = xagg[N,1024] @ BT^T + bias, act, split ----------------
#define AHI_OFF 0
#define ALO_OFF 16384
#define BHI_OFF 32768
#define BLO_OFF 49152

__global__ __launch_bounds__(256, 1) void gemm_out_kernel(
    const unsigned short* __restrict__ aggHi, const unsigned short* __restrict__ aggLo,
    const unsigned short* __restrict__ btHi, const unsigned short* __restrict__ btLo,
    const float* __restrict__ bias, float* __restrict__ outF,
    unsigned short* __restrict__ outHi, unsigned short* __restrict__ outLo, int act_tanh) {
  __shared__ __align__(16) char lds[131072];
  int t = threadIdx.x;
  int lane = t & 63, wv = t >> 6;
  int quad = lane >> 4, lr = lane & 15;
  int row0 = blockIdx.y * 128;
  int col0 = blockIdx.x * 128;
  int wm = (wv & 1) * 64, wn = (wv >> 1) * 64;

  floatx4 acc[4][4];
#pragma unroll
  for (int i = 0; i < 4; i++)
#pragma unroll
    for (int j = 0; j < 4; j++) acc[i][j] = (floatx4){0.f, 0.f, 0.f, 0.f};

  auto stage = [&](int ks, int bufbase) {
#pragma unroll
    for (int mat = 0; mat < 4; mat++) {
      const unsigned short* src = (mat == 0) ? aggHi : (mat == 1) ? aggLo : (mat == 2) ? btHi : btLo;
      int rowbase = (mat < 2) ? row0 : col0;
      int maxrow = (mat < 2) ? (NNODES - 1) : 255;
      int ldsoff = bufbase + mat * 16384;
#pragma unroll
      for (int it = 0; it < 4; it++) {
        int lin = ((wv * 4 + it) << 10) + lane * 16;
        int R = lin >> 7;
        int c = (lin >> 4) & 7;
        int g = c ^ (R & 7);
        int gr = rowbase + R;
        if (gr > maxrow) gr = maxrow;
        const char* gp = (const char*)src + (size_t)gr * 2048 + ks * 128 + g * 16;
        __builtin_amdgcn_global_load_lds(
            (const __attribute__((address_space(1))) void*)gp,
            (__attribute__((address_space(3))) void*)(lds + ldsoff + lin), 16, 0, 0);
      }
    }
  };

  stage(0, 0);
  asm volatile("s_waitcnt vmcnt(0)" ::: "memory");
  __builtin_amdgcn_s_barrier();
  asm volatile("" ::: "memory");

  int cur = 0;
  for (int ks = 0; ks < 16; ks++) {
    if (ks < 15) stage(ks + 1, (cur ^ 1) * 65536);

    int base = cur * 65536;
#pragma unroll
    for (int ksub = 0; ksub < 2; ksub++) {
      int g = ksub * 4 + quad;
      bf16x8 ah[4], al_[4], bh[4], bl[4];
#pragma unroll
      for (int mi = 0; mi < 4; mi++) {
        int m = wm + mi * 16 + lr;
        int off = m * 128 + ((g ^ (m & 7)) << 4);
        ah[mi] = *(const bf16x8*)(lds + base + AHI_OFF + off);
        al_[mi] = *(const bf16x8*)(lds + base + ALO_OFF + off);
      }
#pragma unroll
      for (int ni = 0; ni < 4; ni++) {
        int n = wn + ni * 16 + lr;
        int off = n * 128 + ((g ^ (n & 7)) << 4);
        bh[ni] = *(const bf16x8*)(lds + base + BHI_OFF + off);
        bl[ni] = *(const bf16x8*)(lds + base + BLO_OFF + off);
      }
#pragma unroll
      for (int mi = 0; mi < 4; mi++)
#pragma unroll
        for (int ni = 0; ni < 4; ni++) {
          acc[mi][ni] = __builtin_amdgcn_mfma_f32_16x16x32_bf16(ah[mi], bh[ni], acc[mi][ni], 0, 0, 0);
          acc[mi][ni] = __builtin_amdgcn_mfma_f32_16x16x32_bf16(ah[mi], bl[ni], acc[mi][ni], 0, 0, 0);
          acc[mi][ni] = __builtin_amdgcn_mfma_f32_16x16x32_bf16(al_[mi], bh[ni], acc[mi][ni], 0, 0, 0);
        }
    }

    asm volatile("s_waitcnt vmcnt(0)" ::: "memory");
    __builtin_amdgcn_s_barrier();
    asm volatile("" ::: "memory");
    cur ^= 1;
  }

#pragma unroll
  for (int mi = 0; mi < 4; mi++) {
#pragma unroll
    for (int ni = 0; ni < 4; ni++) {
      int col = col0 + wn + ni * 16 + lr;
      float bv = bias[col];
#pragma unroll
      for (int r = 0; r < 4; r++) {
        int row = row0 + wm + mi * 16 + quad * 4 + r;
        if (row < NNODES) {
          float v = acc[mi][ni][r] + bv;
          v = act_tanh ? tanhf(v) : fmaxf(v, 0.f);
          size_t o = (size_t)row * 256 + col;
          if (outF) outF[o] = v;
          unsigned u = __float_as_uint(v);
          float rr = v - __uint_as_float(u & 0xffff0000u);
          outHi[o] = (unsigned short)(u >> 16);
          outLo[o] = (unsigned short)(__float_as_uint(rr) >> 16);
        }
      }
    }
  }
}

// ---------------- adj = sigmoid(Z @ Z^T), triangular grid, full-line writes (no RFO) ----------------
__global__ __launch_bounds__(256, 2) void zzt_mfma_kernel(
    const unsigned short* __restrict__ zhi, const unsigned short* __restrict__ zlo,
    float* __restrict__ out) {
  __shared__ __align__(16) char lds[65536];
  int t = threadIdx.x;
  int lane = t & 63, wv = t >> 6;
  int quad = lane >> 4, lr = lane & 15;

  int p = blockIdx.x;
  int bi = (int)((159.0f - sqrtf(159.0f * 159.0f - 8.0f * (float)p)) * 0.5f);
  if (bi < 0) bi = 0;
  if (bi > NT - 1) bi = NT - 1;
  while (bi * NT - bi * (bi - 1) / 2 > p) bi--;
  while ((bi + 1) * NT - (bi + 1) * bi / 2 <= p) bi++;
  int bj = bi + (p - (bi * NT - bi * (bi - 1) / 2));
  int row0 = bi * 128;
  int col0 = bj * 128;
  int wm = (wv & 1) * 64, wn = (wv >> 1) * 64;

  floatx4 acc[4][4];
#pragma unroll
  for (int i = 0; i < 4; i++)
#pragma unroll
    for (int j = 0; j < 4; j++) acc[i][j] = (floatx4){0.f, 0.f, 0.f, 0.f};

  for (int ks = 0; ks < 4; ks++) {
#pragma unroll
    for (int mat = 0; mat < 4; mat++) {
      const unsigned short* src = (mat == 0 || mat == 2) ? zhi : zlo;
      int rowbase = (mat < 2) ? row0 : col0;
      int ldsoff = mat * 16384;
#pragma unroll
      for (int it = 0; it < 4; it++) {
        int lin = ((wv * 4 + it) << 10) + lane * 16;
        int R = lin >> 7;
        int c = (lin >> 4) & 7;
        int g = c ^ (R & 7);
        int gr = rowbase + R;
        if (gr > NNODES - 1) gr = NNODES - 1;
        const char* gp = (const char*)src + (size_t)gr * 512 + ks * 128 + g * 16;
        __builtin_amdgcn_global_load_lds(
            (const __attribute__((address_space(1))) void*)gp,
            (__attribute__((address_space(3))) void*)(lds + ldsoff + lin), 16, 0, 0);
      }
    }
    __syncthreads();

#pragma unroll
    for (int ksub = 0; ksub < 2; ksub++) {
      int g = ksub * 4 + quad;
      bf16x8 ah[4], al_[4], bh[4], bl[4];
#pragma unroll
      for (int mi = 0; mi < 4; mi++) {
        int m = wm + mi * 16 + lr;
        int off = m * 128 + ((g ^ (m & 7)) << 4);
        ah[mi] = *(const bf16x8*)(lds + AHI_OFF + off);
        al_[mi] = *(const bf16x8*)(lds + ALO_OFF + off);
      }
#pragma unroll
      for (int ni = 0; ni < 4; ni++) {
        int n = wn + ni * 16 + lr;
        int off = n * 128 + ((g ^ (n & 7)) << 4);
        bh[ni] = *(const bf16x8*)(lds + BHI_OFF + off);
        bl[ni] = *(const bf16x8*)(lds + BLO_OFF + off);
      }
#pragma unroll
      for (int mi = 0; mi < 4; mi++)
#pragma unroll
        for (int ni = 0; ni < 4; ni++) {
          acc[mi][ni] = __builtin_amdgcn_mfma_f32_16x16x32_bf16(ah[mi], bh[ni], acc[mi][ni], 0, 0, 0);
          acc[mi][ni] = __builtin_amdgcn_mfma_f32_16x16x32_bf16(ah[mi], bl[ni], acc[mi][ni], 0, 0, 0);
          acc[mi][ni] = __builtin_amdgcn_mfma_f32_16x16x32_bf16(al_[mi], bh[ni], acc[mi][ni], 0, 0, 0);
        }
    }
    __syncthreads();
  }

  bool diag = (bi == bj);
  float4* ltile = (float4*)lds;        // 128 cols x 32 row-quads, skewed: idx = c*32 + ((rq+c)&31)
  const float* ltf = (const float*)lds;

  // sigmoid -> LDS tile (ALL blocks, diag included)
#pragma unroll
  for (int mi = 0; mi < 4; mi++) {
#pragma unroll
    for (int ni = 0; ni < 4; ni++) {
      int cl = wn + ni * 16 + lr;  // local col
      float4 sv;
      sv.x = 1.f / (1.f + __expf(-acc[mi][ni][0]));
      sv.y = 1.f / (1.f + __expf(-acc[mi][ni][1]));
      sv.z = 1.f / (1.f + __expf(-acc[mi][ni][2]));
      sv.w = 1.f / (1.f + __expf(-acc[mi][ni][3]));
      int rl0 = wm + mi * 16 + quad * 4;  // local row base (multiple of 4)
      int rq = rl0 >> 2;
      ltile[cl * 32 + ((rq + cl) & 31)] = sv;
    }
  }
  __syncthreads();

  // direct row-major writes: half-wave hw writes one row as 32 x float4 = 512B contiguous
  {
    int hw = t >> 5, l = t & 31;
    bool colok = (col0 + 4 * l + 4 <= NNODES);
#pragma unroll
    for (int it = 0; it < 16; it++) {
      int r = it * 8 + hw;
      int row = row0 + r;
      if (colok && row < NNODES) {
        int rq = r >> 2, comp = r & 3;
        float4 v;
#pragma unroll
        for (int j = 0; j < 4; j++) {
          int cc = 4 * l + j;
          ((float*)&v)[j] = ltf[(cc * 32 + ((rq + cc) & 31)) * 4 + comp];
        }
        *reinterpret_cast<float4*>(&out[(size_t)row * NNODES + col0 + 4 * l]) = v;
      }
    }
  }

  if (!diag) {
    // mirror: wave wv covers cols [wv*32, wv*32+32), 2 cols per iter, coalesced rows
#pragma unroll
    for (int it = 0; it < 16; it++) {
      int cl = wv * 32 + it * 2 + (lane >> 5);
      int rq = lane & 31;
      int col = col0 + cl;
      if (col < NNODES) {
        float4 v = ltile[cl * 32 + ((rq + cl) & 31)];
        *reinterpret_cast<float4*>(&out[(size_t)col * NNODES + row0 + 4 * rq]) = v;
      }
    }
  }
}

extern "C" void kernel_launch(void* const* d_in, const int* in_sizes, int n_in,
                              void* d_out, int out_size, void* d_ws, size_t ws_size,
                              hipStream_t stream) {
  const float* x = (const float*)d_in[0];
  const int* ei = (const int*)d_in[1];
  const float* W[4]  = {(const float*)d_in[2], (const float*)d_in[6], (const float*)d_in[10], (const float*)d_in[14]};
  const float* as[4] = {(const float*)d_in[3], (const float*)d_in[7], (const float*)d_in[11], (const float*)d_in[15]};
  const float* ad[4] = {(const float*)d_in[4], (const float*)d_in[8], (const float*)d_in[12], (const float*)d_in[16]};
  const float* bs[4] = {(const float*)d_in[5], (const float*)d_in[9], (const float*)d_in[13], (const float*)d_in[17]};

  char* ws = (char*)d_ws;
  size_t off = 0;
  auto alloc = [&](size_t bytes) -> void* {
    void* p = ws + off;
    off = (off + bytes + 255) & ~(size_t)255;
    return p;
  };
  unsigned short* aggHi = (unsigned short*)alloc(sizeof(unsigned short) * (size_t)NNODES * 1024);
  unsigned short* aggLo = (unsigned short*)alloc(sizeof(unsigned short) * (size_t)NNODES * 1024);
  unsigned short* shi   = (unsigned short*)alloc(sizeof(unsigned short) * (size_t)NNODES * FDIM);
  unsigned short* slo   = (unsigned short*)alloc(sizeof(unsigned short) * (size_t)NNODES * FDIM);
  unsigned short* btHi  = (unsigned short*)alloc(sizeof(unsigned short) * 4 * 256 * 1024);  // per-layer
  unsigned short* btLo  = (unsigned short*)alloc(sizeof(unsigned short) * 4 * 256 * 1024);
  float* al_s  = (float*)alloc(sizeof(float) * NNODES * 4);
  float* al_d  = (float*)alloc(sizeof(float) * NNODES * 4);
  float* Was   = (float*)alloc(sizeof(float) * 4 * 256 * 4);  // per-layer
  float* Wad   = (float*)alloc(sizeof(float) * 4 * 256 * 4);
  int* counts  = (int*)alloc(sizeof(int) * NNODES);
  int* row_ptr = (int*)alloc(sizeof(int) * (NNODES + 1));
  int* fill    = (int*)alloc(sizeof(int) * NNODES);
  int* col_idx = (int*)alloc(sizeof(int) * ETOT);

  hipMemsetAsync(counts, 0, sizeof(int) * NNODES, stream);
  // merged preprocessing: split | bt | wa | count  (13338 blocks)
  preproc_kernel<<<13338, 256, 0, stream>>>(x, ei, W[0], W[1], W[2], W[3],
                                            as[0], as[1], as[2], as[3],
                                            ad[0], ad[1], ad[2], ad[3],
                                            shi, slo, btHi, btLo, Was, Wad, counts);
  scan_kernel<<<1, 256, 0, stream>>>(counts, row_ptr, fill);
  scatter_kernel<<<(ETOT + 255) / 256, 256, 0, stream>>>(ei, fill, col_idx);

  float* z = (float*)d_out + (size_t)NNODES * NNODES;
  for (int l = 0; l < 4; l++) {
    al_kernel<<<(NNODES + 31) / 32, 256, 0, stream>>>(shi, slo, Was + l * 1024, Wad + l * 1024,
                                                      al_s, al_d);
    // PROBE: layer-0 gather x32 (attribute the new feature-split gather)
    gat_gather_kernel<<<NNODES / 2, 256, 0, stream>>>(shi, al_s, al_d, row_ptr, col_idx,
                                                      aggHi, aggLo, l == 0 ? 32 : 1);
    float* outF = (l == 3) ? z : (float*)nullptr;
    gemm_out_kernel<<<dim3(2, 79), 256, 0, stream>>>(aggHi, aggLo,
                                                     btHi + (size_t)l * 262144,
                                                     btLo + (size_t)l * 262144, bs[l],
                                                     outF, shi, slo, l == 3 ? 1 : 0);
  }
  zzt_mfma_kernel<<<NT * (NT + 1) / 2, 256, 0, stream>>>(shi, slo, (float*)d_out);
}

// Round 10
// 1343.934 us; speedup vs baseline: 1.2338x; 1.2338x over previous
//
#include <hip/hip_runtime.h>
#include <hip/hip_bf16.h>

#define NNODES 10000
#define NEDGE_IN 320000
#define ETOT (NEDGE_IN + NNODES)
#define FDIM 256
#define NT 79  // 128-tiles covering 10000

typedef float floatx4 __attribute__((ext_vector_type(4)));
typedef float floatx2 __attribute__((ext_vector_type(2)));
typedef __bf16 bf16x8 __attribute__((ext_vector_type(8)));

__device__ __forceinline__ float bf2f(unsigned short u) {
  return __uint_as_float((unsigned)u << 16);
}

// ---------------- merged preprocessing: split | prep_bt | prep_wa | count_deg ----------------
// Block ranges: [0,10000) split, [10000,11024) bt, [11024,12048) wa, [12048,13338) count.
__global__ __launch_bounds__(256) void preproc_kernel(
    const float* __restrict__ x, const int* __restrict__ ei,
    const float* __restrict__ W0, const float* __restrict__ W1,
    const float* __restrict__ W2, const float* __restrict__ W3,
    const float* __restrict__ as0, const float* __restrict__ as1,
    const float* __restrict__ as2, const float* __restrict__ as3,
    const float* __restrict__ ad0, const float* __restrict__ ad1,
    const float* __restrict__ ad2, const float* __restrict__ ad3,
    unsigned short* __restrict__ shi, unsigned short* __restrict__ slo,
    unsigned short* __restrict__ btHi, unsigned short* __restrict__ btLo,
    float* __restrict__ Was, float* __restrict__ Wad, int* __restrict__ counts) {
  __shared__ float smem[32 * 33];
  int b = blockIdx.x, t = threadIdx.x;
  if (b < 10000) {
    int i = b * 256 + t;
    float v = x[i];
    unsigned u = __float_as_uint(v);
    float r = v - __uint_as_float(u & 0xffff0000u);
    shi[i] = (unsigned short)(u >> 16);
    slo[i] = (unsigned short)(__float_as_uint(r) >> 16);
  } else if (b < 11024) {
    int idx = b - 10000;
    int fx = idx & 7, ky = (idx >> 3) & 7, zi = idx >> 6;
    int h = zi & 3, lay = zi >> 2;
    const float* W = (lay == 0) ? W0 : (lay == 1) ? W1 : (lay == 2) ? W2 : W3;
    size_t lofs = (size_t)lay * 262144;
    float(*tile)[33] = (float(*)[33])smem;
    int tx = t & 31, ty = t >> 5;
    int f0 = fx * 32, k0 = ky * 32;
#pragma unroll
    for (int i = 0; i < 4; i++) {
      int kr = ty + 8 * i;
      tile[kr][tx] = W[(size_t)(k0 + kr) * 1024 + h * 256 + f0 + tx];
    }
    __syncthreads();
#pragma unroll
    for (int i = 0; i < 4; i++) {
      int fr = ty + 8 * i;
      float v = 0.25f * tile[tx][fr];
      unsigned u = __float_as_uint(v);
      float r = v - __uint_as_float(u & 0xffff0000u);
      size_t o = lofs + (size_t)(f0 + fr) * 1024 + h * 256 + k0 + tx;
      btHi[o] = (unsigned short)(u >> 16);
      btLo[o] = (unsigned short)(__float_as_uint(r) >> 16);
    }
  } else if (b < 12048) {
    int idx = b - 11024;
    int k = idx & 255, lay = idx >> 8;
    const float* W = (lay == 0) ? W0 : (lay == 1) ? W1 : (lay == 2) ? W2 : W3;
    const float* a_src = (lay == 0) ? as0 : (lay == 1) ? as1 : (lay == 2) ? as2 : as3;
    const float* a_dst = (lay == 0) ? ad0 : (lay == 1) ? ad1 : (lay == 2) ? ad2 : ad3;
    float ps[4], pd[4];
#pragma unroll
    for (int hd = 0; hd < 4; hd++) {
      float w = W[(size_t)k * 1024 + hd * 256 + t];
      ps[hd] = w * a_src[hd * 256 + t];
      pd[hd] = w * a_dst[hd * 256 + t];
    }
    float(*red)[4] = (float(*)[4])smem;
    int lane = t & 63, wv = t >> 6;
#pragma unroll
    for (int q = 0; q < 8; q++) {
      float v = (q < 4) ? ps[q] : pd[q - 4];
#pragma unroll
      for (int off = 32; off > 0; off >>= 1) v += __shfl_down(v, off, 64);
      if (lane == 0) red[q][wv] = v;
    }
    __syncthreads();
    if (t < 8) {
      float v = red[t][0] + red[t][1] + red[t][2] + red[t][3];
      if (t < 4) Was[lay * 1024 + k * 4 + t] = v;
      else Wad[lay * 1024 + k * 4 + (t - 4)] = v;
    }
  } else {
    int e = (b - 12048) * 256 + t;
    if (e < ETOT) {
      int d = (e < NEDGE_IN) ? ei[NEDGE_IN + e] : (e - NEDGE_IN);
      atomicAdd(&counts[d], 1);
    }
  }
}

__global__ __launch_bounds__(256) void scan_kernel(const int* __restrict__ counts,
                                                   int* __restrict__ row_ptr,
                                                   int* __restrict__ fill) {
  int t = threadIdx.x;
  const int CH = 40;
  int base = t * CH;
  int local[CH];
  int sum = 0;
#pragma unroll
  for (int i = 0; i < CH; i++) {
    int idx = base + i;
    int v = (idx < NNODES) ? counts[idx] : 0;
    local[i] = sum;
    sum += v;
  }
  __shared__ int ssum[256];
  ssum[t] = sum;
  __syncthreads();
  for (int off = 1; off < 256; off <<= 1) {
    int add = (t >= off) ? ssum[t - off] : 0;
    __syncthreads();
    ssum[t] += add;
    __syncthreads();
  }
  int excl = ssum[t] - sum;
#pragma unroll
  for (int i = 0; i < CH; i++) {
    int idx = base + i;
    if (idx < NNODES) {
      int v = excl + local[i];
      row_ptr[idx] = v;
      fill[idx] = v;
    }
  }
  if (t == 255) row_ptr[NNODES] = ssum[255];
}

__global__ void scatter_kernel(const int* __restrict__ ei, int* __restrict__ fill,
                               int* __restrict__ col_idx) {
  int e = blockIdx.x * blockDim.x + threadIdx.x;
  if (e >= ETOT) return;
  int s, d;
  if (e < NEDGE_IN) { s = ei[e]; d = ei[NEDGE_IN + e]; } else { s = d = e - NEDGE_IN; }
  int pos = atomicAdd(&fill[d], 1);
  col_idx[pos] = s;
}

// ---------------- al_s/al_d[n,h] = X[n,:] @ Was/Wad  (8 threads/node, 3-step DPP reduce) ----------------
__global__ __launch_bounds__(256) void al_kernel(const unsigned short* __restrict__ xhi,
                                                 const unsigned short* __restrict__ xlo,
                                                 const float* __restrict__ Was,
                                                 const float* __restrict__ Wad,
                                                 float* __restrict__ al_s,
                                                 float* __restrict__ al_d) {
  int t = threadIdx.x;
  int kslot = t & 7;
  int nslot = t >> 3;
  int node = blockIdx.x * 32 + nslot;
  int nc = node < NNODES ? node : NNODES - 1;
  const unsigned short* rh = xhi + (size_t)nc * 256;
  const unsigned short* rl = xlo + (size_t)nc * 256;
  float ps[4] = {0.f, 0.f, 0.f, 0.f}, pd[4] = {0.f, 0.f, 0.f, 0.f};
#pragma unroll
  for (int j = 0; j < 8; j++) {
    int k0 = j * 32 + kslot * 4;
    ushort4 h4 = *reinterpret_cast<const ushort4*>(rh + k0);
    ushort4 l4 = *reinterpret_cast<const ushort4*>(rl + k0);
    float xv[4] = {bf2f(h4.x) + bf2f(l4.x), bf2f(h4.y) + bf2f(l4.y),
                   bf2f(h4.z) + bf2f(l4.z), bf2f(h4.w) + bf2f(l4.w)};
#pragma unroll
    for (int m = 0; m < 4; m++) {
      float4 ws = *reinterpret_cast<const float4*>(Was + (k0 + m) * 4);
      float4 wd = *reinterpret_cast<const float4*>(Wad + (k0 + m) * 4);
      ps[0] += xv[m] * ws.x; ps[1] += xv[m] * ws.y; ps[2] += xv[m] * ws.z; ps[3] += xv[m] * ws.w;
      pd[0] += xv[m] * wd.x; pd[1] += xv[m] * wd.y; pd[2] += xv[m] * wd.z; pd[3] += xv[m] * wd.w;
    }
  }
#pragma unroll
  for (int d = 4; d > 0; d >>= 1) {
#pragma unroll
    for (int q = 0; q < 4; q++) {
      ps[q] += __shfl_down(ps[q], d, 64);
      pd[q] += __shfl_down(pd[q], d, 64);
    }
  }
  if (kslot == 0 && node < NNODES) {
    *reinterpret_cast<float4*>(al_s + node * 4) = make_float4(ps[0], ps[1], ps[2], ps[3]);
    *reinterpret_cast<float4*>(al_d + node * 4) = make_float4(pd[0], pd[1], pd[2], pd[3]);
  }
}

// ---------------- gather: REVERTED to R7 form — 1 wave/node, uint2 loads, packed-f32 fma ----------------
// R9's 2-wave feature-split REGRESSED (25.6 vs est ~15): it halved pk_fma/lane but duplicated
// fixed per-edge costs (sS/sE ds_reads, softmax, loop) across both waves -> +20% total instrs.
#define ACCP(ux, ev)                                                                     \
  {                                                                                      \
    floatx2 _f01 = {__uint_as_float(ux.x << 16), __uint_as_float(ux.x & 0xffff0000u)};   \
    floatx2 _f23 = {__uint_as_float(ux.y << 16), __uint_as_float(ux.y & 0xffff0000u)};   \
    floatx2 _b0 = {ev.x, ev.x}, _b1 = {ev.y, ev.y}, _b2 = {ev.z, ev.z}, _b3 = {ev.w, ev.w}; \
    acc2[0][0] += _f01 * _b0; acc2[0][1] += _f23 * _b0;                                  \
    acc2[1][0] += _f01 * _b1; acc2[1][1] += _f23 * _b1;                                  \
    acc2[2][0] += _f01 * _b2; acc2[2][1] += _f23 * _b2;                                  \
    acc2[3][0] += _f01 * _b3; acc2[3][1] += _f23 * _b3;                                  \
  }

__global__ __launch_bounds__(256) void gat_gather_kernel(
    const unsigned short* __restrict__ xhi, const float* __restrict__ al_s,
    const float* __restrict__ al_d, const int* __restrict__ row_ptr,
    const int* __restrict__ col_idx,
    unsigned short* __restrict__ aggHi, unsigned short* __restrict__ aggLo, int rep) {
  __shared__ int sS[4][64];
  __shared__ float4 sE[4][64];
  int t = threadIdx.x;
  int lane = t & 63, wv = t >> 6;
  int n = blockIdx.x * 4 + wv;
  int start = row_ptr[n], end = row_ptr[n + 1];
  float4 ald4 = *reinterpret_cast<const float4*>(al_d + n * 4);
  float ald[4] = {ald4.x, ald4.y, ald4.z, ald4.w};
  const unsigned short* xl = xhi + lane * 4;

#pragma unroll 1
  for (int rp = 0; rp < rep; rp++) {
    floatx2 acc2[4][2];
#pragma unroll
    for (int h = 0; h < 4; h++) {
      acc2[h][0] = (floatx2){0.f, 0.f};
      acc2[h][1] = (floatx2){0.f, 0.f};
    }
    float esum[4] = {0.f, 0.f, 0.f, 0.f};

    for (int c = start; c < end; c += 64) {
      int nch = min(64, end - c);
      int s = 0;
      float ex[4] = {0.f, 0.f, 0.f, 0.f};
      if (lane < nch) {
        s = col_idx[c + lane];
        float4 as4 = *reinterpret_cast<const float4*>(al_s + s * 4);
        float lv[4] = {as4.x + ald[0], as4.y + ald[1], as4.z + ald[2], as4.w + ald[3]};
#pragma unroll
        for (int h = 0; h < 4; h++) {
          float l = lv[h];
          l = (l > 0.f) ? l : 0.2f * l;
          l = fminf(l, 60.f);
          float e = __expf(l);
          ex[h] = e;
          esum[h] += e;
        }
      }
      sS[wv][lane] = s;
      sE[wv][lane] = make_float4(ex[0], ex[1], ex[2], ex[3]);
      __asm__ __volatile__("" ::: "memory");  // per-wave LDS ops are in-order; pin compiler order
      int i = 0;
      for (; i + 4 <= nch; i += 4) {
        int s0 = sS[wv][i], s1 = sS[wv][i + 1], s2 = sS[wv][i + 2], s3 = sS[wv][i + 3];
        float4 e0 = sE[wv][i], e1 = sE[wv][i + 1], e2 = sE[wv][i + 2], e3 = sE[wv][i + 3];
        uint2 x0 = *reinterpret_cast<const uint2*>(xl + (size_t)s0 * 256);
        uint2 x1 = *reinterpret_cast<const uint2*>(xl + (size_t)s1 * 256);
        uint2 x2 = *reinterpret_cast<const uint2*>(xl + (size_t)s2 * 256);
        uint2 x3 = *reinterpret_cast<const uint2*>(xl + (size_t)s3 * 256);
        ACCP(x0, e0);
        ACCP(x1, e1);
        ACCP(x2, e2);
        ACCP(x3, e3);
      }
      for (; i < nch; i++) {
        int s0 = sS[wv][i];
        float4 e0 = sE[wv][i];
        uint2 x0 = *reinterpret_cast<const uint2*>(xl + (size_t)s0 * 256);
        ACCP(x0, e0);
      }
      __asm__ __volatile__("" ::: "memory");
    }

#pragma unroll
    for (int h = 0; h < 4; h++) {
#pragma unroll
      for (int m = 32; m > 0; m >>= 1) esum[h] += __shfl_xor(esum[h], m, 64);
    }

#pragma unroll
    for (int h = 0; h < 4; h++) {
      float inv = 1.f / (esum[h] + 1e-16f);
      float av[4] = {acc2[h][0].x, acc2[h][0].y, acc2[h][1].x, acc2[h][1].y};
      ushort4 hv, lv;
      unsigned short* hp = (unsigned short*)&hv;
      unsigned short* lp = (unsigned short*)&lv;
#pragma unroll
      for (int j = 0; j < 4; j++) {
        float v = av[j] * inv;
        unsigned u = __float_as_uint(v);
        float r = v - __uint_as_float(u & 0xffff0000u);
        hp[j] = (unsigned short)(u >> 16);
        lp[j] = (unsigned short)(__float_as_uint(r) >> 16);
      }
      size_t o = (size_t)n * 1024 + h * 256 + lane * 4;
      *reinterpret_cast<ushort4*>(aggHi + o) = hv;
      *reinterpret_cast<ushort4*>(aggLo + o) = lv;
    }
  }
}

// ---------------- MFMA GEMM: out[N,256] = xagg[N,1024] @ BT^T + bias, act, split ----------------
#define AHI_OFF 0
#define ALO_OFF 16384
#define BHI_OFF 32768
#define BLO_OFF 49152

__global__ __launch_bounds__(256, 1) void gemm_out_kernel(
    const unsigned short* __restrict__ aggHi, const unsigned short* __restrict__ aggLo,
    const unsigned short* __restrict__ btHi, const unsigned short* __restrict__ btLo,
    const float* __restrict__ bias, float* __restrict__ outF,
    unsigned short* __restrict__ outHi, unsigned short* __restrict__ outLo, int act_tanh) {
  __shared__ __align__(16) char lds[131072];
  int t = threadIdx.x;
  int lane = t & 63, wv = t >> 6;
  int quad = lane >> 4, lr = lane & 15;
  int row0 = blockIdx.y * 128;
  int col0 = blockIdx.x * 128;
  int wm = (wv & 1) * 64, wn = (wv >> 1) * 64;

  floatx4 acc[4][4];
#pragma unroll
  for (int i = 0; i < 4; i++)
#pragma unroll
    for (int j = 0; j < 4; j++) acc[i][j] = (floatx4){0.f, 0.f, 0.f, 0.f};

  auto stage = [&](int ks, int bufbase) {
#pragma unroll
    for (int mat = 0; mat < 4; mat++) {
      const unsigned short* src = (mat == 0) ? aggHi : (mat == 1) ? aggLo : (mat == 2) ? btHi : btLo;
      int rowbase = (mat < 2) ? row0 : col0;
      int maxrow = (mat < 2) ? (NNODES - 1) : 255;
      int ldsoff = bufbase + mat * 16384;
#pragma unroll
      for (int it = 0; it < 4; it++) {
        int lin = ((wv * 4 + it) << 10) + lane * 16;
        int R = lin >> 7;
        int c = (lin >> 4) & 7;
        int g = c ^ (R & 7);
        int gr = rowbase + R;
        if (gr > maxrow) gr = maxrow;
        const char* gp = (const char*)src + (size_t)gr * 2048 + ks * 128 + g * 16;
        __builtin_amdgcn_global_load_lds(
            (const __attribute__((address_space(1))) void*)gp,
            (__attribute__((address_space(3))) void*)(lds + ldsoff + lin), 16, 0, 0);
      }
    }
  };

  stage(0, 0);
  asm volatile("s_waitcnt vmcnt(0)" ::: "memory");
  __builtin_amdgcn_s_barrier();
  asm volatile("" ::: "memory");

  int cur = 0;
  for (int ks = 0; ks < 16; ks++) {
    if (ks < 15) stage(ks + 1, (cur ^ 1) * 65536);

    int base = cur * 65536;
#pragma unroll
    for (int ksub = 0; ksub < 2; ksub++) {
      int g = ksub * 4 + quad;
      bf16x8 ah[4], al_[4], bh[4], bl[4];
#pragma unroll
      for (int mi = 0; mi < 4; mi++) {
        int m = wm + mi * 16 + lr;
        int off = m * 128 + ((g ^ (m & 7)) << 4);
        ah[mi] = *(const bf16x8*)(lds + base + AHI_OFF + off);
        al_[mi] = *(const bf16x8*)(lds + base + ALO_OFF + off);
      }
#pragma unroll
      for (int ni = 0; ni < 4; ni++) {
        int n = wn + ni * 16 + lr;
        int off = n * 128 + ((g ^ (n & 7)) << 4);
        bh[ni] = *(const bf16x8*)(lds + base + BHI_OFF + off);
        bl[ni] = *(const bf16x8*)(lds + base + BLO_OFF + off);
      }
#pragma unroll
      for (int mi = 0; mi < 4; mi++)
#pragma unroll
        for (int ni = 0; ni < 4; ni++) {
          acc[mi][ni] = __builtin_amdgcn_mfma_f32_16x16x32_bf16(ah[mi], bh[ni], acc[mi][ni], 0, 0, 0);
          acc[mi][ni] = __builtin_amdgcn_mfma_f32_16x16x32_bf16(ah[mi], bl[ni], acc[mi][ni], 0, 0, 0);
          acc[mi][ni] = __builtin_amdgcn_mfma_f32_16x16x32_bf16(al_[mi], bh[ni], acc[mi][ni], 0, 0, 0);
        }
    }

    asm volatile("s_waitcnt vmcnt(0)" ::: "memory");
    __builtin_amdgcn_s_barrier();
    asm volatile("" ::: "memory");
    cur ^= 1;
  }

#pragma unroll
  for (int mi = 0; mi < 4; mi++) {
#pragma unroll
    for (int ni = 0; ni < 4; ni++) {
      int col = col0 + wn + ni * 16 + lr;
      float bv = bias[col];
#pragma unroll
      for (int r = 0; r < 4; r++) {
        int row = row0 + wm + mi * 16 + quad * 4 + r;
        if (row < NNODES) {
          float v = acc[mi][ni][r] + bv;
          v = act_tanh ? tanhf(v) : fmaxf(v, 0.f);
          size_t o = (size_t)row * 256 + col;
          if (outF) outF[o] = v;
          unsigned u = __float_as_uint(v);
          float rr = v - __uint_as_float(u & 0xffff0000u);
          outHi[o] = (unsigned short)(u >> 16);
          outLo[o] = (unsigned short)(__float_as_uint(rr) >> 16);
        }
      }
    }
  }
}

// ---------------- adj = sigmoid(Z @ Z^T), triangular grid, full-line writes (no RFO) ----------------
__global__ __launch_bounds__(256, 2) void zzt_mfma_kernel(
    const unsigned short* __restrict__ zhi, const unsigned short* __restrict__ zlo,
    float* __restrict__ out) {
  __shared__ __align__(16) char lds[65536];
  int t = threadIdx.x;
  int lane = t & 63, wv = t >> 6;
  int quad = lane >> 4, lr = lane & 15;

  int p = blockIdx.x;
  int bi = (int)((159.0f - sqrtf(159.0f * 159.0f - 8.0f * (float)p)) * 0.5f);
  if (bi < 0) bi = 0;
  if (bi > NT - 1) bi = NT - 1;
  while (bi * NT - bi * (bi - 1) / 2 > p) bi--;
  while ((bi + 1) * NT - (bi + 1) * bi / 2 <= p) bi++;
  int bj = bi + (p - (bi * NT - bi * (bi - 1) / 2));
  int row0 = bi * 128;
  int col0 = bj * 128;
  int wm = (wv & 1) * 64, wn = (wv >> 1) * 64;

  floatx4 acc[4][4];
#pragma unroll
  for (int i = 0; i < 4; i++)
#pragma unroll
    for (int j = 0; j < 4; j++) acc[i][j] = (floatx4){0.f, 0.f, 0.f, 0.f};

  for (int ks = 0; ks < 4; ks++) {
#pragma unroll
    for (int mat = 0; mat < 4; mat++) {
      const unsigned short* src = (mat == 0 || mat == 2) ? zhi : zlo;
      int rowbase = (mat < 2) ? row0 : col0;
      int ldsoff = mat * 16384;
#pragma unroll
      for (int it = 0; it < 4; it++) {
        int lin = ((wv * 4 + it) << 10) + lane * 16;
        int R = lin >> 7;
        int c = (lin >> 4) & 7;
        int g = c ^ (R & 7);
        int gr = rowbase + R;
        if (gr > NNODES - 1) gr = NNODES - 1;
        const char* gp = (const char*)src + (size_t)gr * 512 + ks * 128 + g * 16;
        __builtin_amdgcn_global_load_lds(
            (const __attribute__((address_space(1))) void*)gp,
            (__attribute__((address_space(3))) void*)(lds + ldsoff + lin), 16, 0, 0);
      }
    }
    __syncthreads();

#pragma unroll
    for (int ksub = 0; ksub < 2; ksub++) {
      int g = ksub * 4 + quad;
      bf16x8 ah[4], al_[4], bh[4], bl[4];
#pragma unroll
      for (int mi = 0; mi < 4; mi++) {
        int m = wm + mi * 16 + lr;
        int off = m * 128 + ((g ^ (m & 7)) << 4);
        ah[mi] = *(const bf16x8*)(lds + AHI_OFF + off);
        al_[mi] = *(const bf16x8*)(lds + ALO_OFF + off);
      }
#pragma unroll
      for (int ni = 0; ni < 4; ni++) {
        int n = wn + ni * 16 + lr;
        int off = n * 128 + ((g ^ (n & 7)) << 4);
        bh[ni] = *(const bf16x8*)(lds + BHI_OFF + off);
        bl[ni] = *(const bf16x8*)(lds + BLO_OFF + off);
      }
#pragma unroll
      for (int mi = 0; mi < 4; mi++)
#pragma unroll
        for (int ni = 0; ni < 4; ni++) {
          acc[mi][ni] = __builtin_amdgcn_mfma_f32_16x16x32_bf16(ah[mi], bh[ni], acc[mi][ni], 0, 0, 0);
          acc[mi][ni] = __builtin_amdgcn_mfma_f32_16x16x32_bf16(ah[mi], bl[ni], acc[mi][ni], 0, 0, 0);
          acc[mi][ni] = __builtin_amdgcn_mfma_f32_16x16x32_bf16(al_[mi], bh[ni], acc[mi][ni], 0, 0, 0);
        }
    }
    __syncthreads();
  }

  bool diag = (bi == bj);
  float4* ltile = (float4*)lds;
  const float* ltf = (const float*)lds;

#pragma unroll
  for (int mi = 0; mi < 4; mi++) {
#pragma unroll
    for (int ni = 0; ni < 4; ni++) {
      int cl = wn + ni * 16 + lr;
      float4 sv;
      sv.x = 1.f / (1.f + __expf(-acc[mi][ni][0]));
      sv.y = 1.f / (1.f + __expf(-acc[mi][ni][1]));
      sv.z = 1.f / (1.f + __expf(-acc[mi][ni][2]));
      sv.w = 1.f / (1.f + __expf(-acc[mi][ni][3]));
      int rl0 = wm + mi * 16 + quad * 4;
      int rq = rl0 >> 2;
      ltile[cl * 32 + ((rq + cl) & 31)] = sv;
    }
  }
  __syncthreads();

  {
    int hw = t >> 5, l = t & 31;
    bool colok = (col0 + 4 * l + 4 <= NNODES);
#pragma unroll
    for (int it = 0; it < 16; it++) {
      int r = it * 8 + hw;
      int row = row0 + r;
      if (colok && row < NNODES) {
        int rq = r >> 2, comp = r & 3;
        float4 v;
#pragma unroll
        for (int j = 0; j < 4; j++) {
          int cc = 4 * l + j;
          ((float*)&v)[j] = ltf[(cc * 32 + ((rq + cc) & 31)) * 4 + comp];
        }
        *reinterpret_cast<float4*>(&out[(size_t)row * NNODES + col0 + 4 * l]) = v;
      }
    }
  }

  if (!diag) {
#pragma unroll
    for (int it = 0; it < 16; it++) {
      int cl = wv * 32 + it * 2 + (lane >> 5);
      int rq = lane & 31;
      int col = col0 + cl;
      if (col < NNODES) {
        float4 v = ltile[cl * 32 + ((rq + cl) & 31)];
        *reinterpret_cast<float4*>(&out[(size_t)col * NNODES + row0 + 4 * rq]) = v;
      }
    }
  }
}

extern "C" void kernel_launch(void* const* d_in, const int* in_sizes, int n_in,
                              void* d_out, int out_size, void* d_ws, size_t ws_size,
                              hipStream_t stream) {
  const float* x = (const float*)d_in[0];
  const int* ei = (const int*)d_in[1];
  const float* W[4]  = {(const float*)d_in[2], (const float*)d_in[6], (const float*)d_in[10], (const float*)d_in[14]};
  const float* as[4] = {(const float*)d_in[3], (const float*)d_in[7], (const float*)d_in[11], (const float*)d_in[15]};
  const float* ad[4] = {(const float*)d_in[4], (const float*)d_in[8], (const float*)d_in[12], (const float*)d_in[16]};
  const float* bs[4] = {(const float*)d_in[5], (const float*)d_in[9], (const float*)d_in[13], (const float*)d_in[17]};

  char* ws = (char*)d_ws;
  size_t off = 0;
  auto alloc = [&](size_t bytes) -> void* {
    void* p = ws + off;
    off = (off + bytes + 255) & ~(size_t)255;
    return p;
  };
  unsigned short* aggHi = (unsigned short*)alloc(sizeof(unsigned short) * (size_t)NNODES * 1024);
  unsigned short* aggLo = (unsigned short*)alloc(sizeof(unsigned short) * (size_t)NNODES * 1024);
  unsigned short* shi   = (unsigned short*)alloc(sizeof(unsigned short) * (size_t)NNODES * FDIM);
  unsigned short* slo   = (unsigned short*)alloc(sizeof(unsigned short) * (size_t)NNODES * FDIM);
  unsigned short* btHi  = (unsigned short*)alloc(sizeof(unsigned short) * 4 * 256 * 1024);
  unsigned short* btLo  = (unsigned short*)alloc(sizeof(unsigned short) * 4 * 256 * 1024);
  float* al_s  = (float*)alloc(sizeof(float) * NNODES * 4);
  float* al_d  = (float*)alloc(sizeof(float) * NNODES * 4);
  float* Was   = (float*)alloc(sizeof(float) * 4 * 256 * 4);
  float* Wad   = (float*)alloc(sizeof(float) * 4 * 256 * 4);
  int* counts  = (int*)alloc(sizeof(int) * NNODES);
  int* row_ptr = (int*)alloc(sizeof(int) * (NNODES + 1));
  int* fill    = (int*)alloc(sizeof(int) * NNODES);
  int* col_idx = (int*)alloc(sizeof(int) * ETOT);

  hipMemsetAsync(counts, 0, sizeof(int) * NNODES, stream);
  preproc_kernel<<<13338, 256, 0, stream>>>(x, ei, W[0], W[1], W[2], W[3],
                                            as[0], as[1], as[2], as[3],
                                            ad[0], ad[1], ad[2], ad[3],
                                            shi, slo, btHi, btLo, Was, Wad, counts);
  scan_kernel<<<1, 256, 0, stream>>>(counts, row_ptr, fill);
  scatter_kernel<<<(ETOT + 255) / 256, 256, 0, stream>>>(ei, fill, col_idx);

  float* z = (float*)d_out + (size_t)NNODES * NNODES;
  for (int l = 0; l < 4; l++) {
    al_kernel<<<(NNODES + 31) / 32, 256, 0, stream>>>(shi, slo, Was + l * 1024, Wad + l * 1024,
                                                      al_s, al_d);
    // PROBE: layer-0 gather x24 (isolate the reverted R7-form gather)
    gat_gather_kernel<<<NNODES / 4, 256, 0, stream>>>(shi, al_s, al_d, row_ptr, col_idx,
                                                      aggHi, aggLo, l == 0 ? 24 : 1);
    float* outF = (l == 3) ? z : (float*)nullptr;
    gemm_out_kernel<<<dim3(2, 79), 256, 0, stream>>>(aggHi, aggLo,
                                                     btHi + (size_t)l * 262144,
                                                     btLo + (size_t)l * 262144, bs[l],
                                                     outF, shi, slo, l == 3 ? 1 : 0);
  }
  zzt_mfma_kernel<<<NT * (NT + 1) / 2, 256, 0, stream>>>(shi, slo, (float*)d_out);
}

// Round 11
// 892.254 us; speedup vs baseline: 1.8584x; 1.5062x over previous
//
#include <hip/hip_runtime.h>
#include <hip/hip_bf16.h>

#define NNODES 10000
#define NEDGE_IN 320000
#define ETOT (NEDGE_IN + NNODES)
#define FDIM 256
#define NT 79  // 128-tiles covering 10000

typedef float floatx4 __attribute__((ext_vector_type(4)));
typedef float floatx2 __attribute__((ext_vector_type(2)));
typedef __bf16 bf16x8 __attribute__((ext_vector_type(8)));

__device__ __forceinline__ float bf2f(unsigned short u) {
  return __uint_as_float((unsigned)u << 16);
}

// ---------------- merged preprocessing: split | prep_bt | prep_wa | count_deg ----------------
// Block ranges: [0,10000) split, [10000,11024) bt, [11024,12048) wa, [12048,13338) count.
__global__ __launch_bounds__(256) void preproc_kernel(
    const float* __restrict__ x, const int* __restrict__ ei,
    const float* __restrict__ W0, const float* __restrict__ W1,
    const float* __restrict__ W2, const float* __restrict__ W3,
    const float* __restrict__ as0, const float* __restrict__ as1,
    const float* __restrict__ as2, const float* __restrict__ as3,
    const float* __restrict__ ad0, const float* __restrict__ ad1,
    const float* __restrict__ ad2, const float* __restrict__ ad3,
    unsigned short* __restrict__ shi, unsigned short* __restrict__ slo,
    unsigned short* __restrict__ btHi, unsigned short* __restrict__ btLo,
    float* __restrict__ Was, float* __restrict__ Wad, int* __restrict__ counts) {
  __shared__ float smem[32 * 33];
  int b = blockIdx.x, t = threadIdx.x;
  if (b < 10000) {
    int i = b * 256 + t;
    float v = x[i];
    unsigned u = __float_as_uint(v);
    float r = v - __uint_as_float(u & 0xffff0000u);
    shi[i] = (unsigned short)(u >> 16);
    slo[i] = (unsigned short)(__float_as_uint(r) >> 16);
  } else if (b < 11024) {
    int idx = b - 10000;
    int fx = idx & 7, ky = (idx >> 3) & 7, zi = idx >> 6;
    int h = zi & 3, lay = zi >> 2;
    const float* W = (lay == 0) ? W0 : (lay == 1) ? W1 : (lay == 2) ? W2 : W3;
    size_t lofs = (size_t)lay * 262144;
    float(*tile)[33] = (float(*)[33])smem;
    int tx = t & 31, ty = t >> 5;
    int f0 = fx * 32, k0 = ky * 32;
#pragma unroll
    for (int i = 0; i < 4; i++) {
      int kr = ty + 8 * i;
      tile[kr][tx] = W[(size_t)(k0 + kr) * 1024 + h * 256 + f0 + tx];
    }
    __syncthreads();
#pragma unroll
    for (int i = 0; i < 4; i++) {
      int fr = ty + 8 * i;
      float v = 0.25f * tile[tx][fr];
      unsigned u = __float_as_uint(v);
      float r = v - __uint_as_float(u & 0xffff0000u);
      size_t o = lofs + (size_t)(f0 + fr) * 1024 + h * 256 + k0 + tx;
      btHi[o] = (unsigned short)(u >> 16);
      btLo[o] = (unsigned short)(__float_as_uint(r) >> 16);
    }
  } else if (b < 12048) {
    int idx = b - 11024;
    int k = idx & 255, lay = idx >> 8;
    const float* W = (lay == 0) ? W0 : (lay == 1) ? W1 : (lay == 2) ? W2 : W3;
    const float* a_src = (lay == 0) ? as0 : (lay == 1) ? as1 : (lay == 2) ? as2 : as3;
    const float* a_dst = (lay == 0) ? ad0 : (lay == 1) ? ad1 : (lay == 2) ? ad2 : ad3;
    float ps[4], pd[4];
#pragma unroll
    for (int hd = 0; hd < 4; hd++) {
      float w = W[(size_t)k * 1024 + hd * 256 + t];
      ps[hd] = w * a_src[hd * 256 + t];
      pd[hd] = w * a_dst[hd * 256 + t];
    }
    float(*red)[4] = (float(*)[4])smem;
    int lane = t & 63, wv = t >> 6;
#pragma unroll
    for (int q = 0; q < 8; q++) {
      float v = (q < 4) ? ps[q] : pd[q - 4];
#pragma unroll
      for (int off = 32; off > 0; off >>= 1) v += __shfl_down(v, off, 64);
      if (lane == 0) red[q][wv] = v;
    }
    __syncthreads();
    if (t < 8) {
      float v = red[t][0] + red[t][1] + red[t][2] + red[t][3];
      if (t < 4) Was[lay * 1024 + k * 4 + t] = v;
      else Wad[lay * 1024 + k * 4 + (t - 4)] = v;
    }
  } else {
    int e = (b - 12048) * 256 + t;
    if (e < ETOT) {
      int d = (e < NEDGE_IN) ? ei[NEDGE_IN + e] : (e - NEDGE_IN);
      atomicAdd(&counts[d], 1);
    }
  }
}

__global__ __launch_bounds__(256) void scan_kernel(const int* __restrict__ counts,
                                                   int* __restrict__ row_ptr,
                                                   int* __restrict__ fill) {
  int t = threadIdx.x;
  const int CH = 40;
  int base = t * CH;
  int local[CH];
  int sum = 0;
#pragma unroll
  for (int i = 0; i < CH; i++) {
    int idx = base + i;
    int v = (idx < NNODES) ? counts[idx] : 0;
    local[i] = sum;
    sum += v;
  }
  __shared__ int ssum[256];
  ssum[t] = sum;
  __syncthreads();
  for (int off = 1; off < 256; off <<= 1) {
    int add = (t >= off) ? ssum[t - off] : 0;
    __syncthreads();
    ssum[t] += add;
    __syncthreads();
  }
  int excl = ssum[t] - sum;
#pragma unroll
  for (int i = 0; i < CH; i++) {
    int idx = base + i;
    if (idx < NNODES) {
      int v = excl + local[i];
      row_ptr[idx] = v;
      fill[idx] = v;
    }
  }
  if (t == 255) row_ptr[NNODES] = ssum[255];
}

__global__ void scatter_kernel(const int* __restrict__ ei, int* __restrict__ fill,
                               int* __restrict__ col_idx) {
  int e = blockIdx.x * blockDim.x + threadIdx.x;
  if (e >= ETOT) return;
  int s, d;
  if (e < NEDGE_IN) { s = ei[e]; d = ei[NEDGE_IN + e]; } else { s = d = e - NEDGE_IN; }
  int pos = atomicAdd(&fill[d], 1);
  col_idx[pos] = s;
}

// ---------------- al_s/al_d[n,h] = X[n,:] @ Was/Wad  (8 threads/node, 3-step DPP reduce) ----------------
__global__ __launch_bounds__(256) void al_kernel(const unsigned short* __restrict__ xhi,
                                                 const unsigned short* __restrict__ xlo,
                                                 const float* __restrict__ Was,
                                                 const float* __restrict__ Wad,
                                                 float* __restrict__ al_s,
                                                 float* __restrict__ al_d) {
  int t = threadIdx.x;
  int kslot = t & 7;
  int nslot = t >> 3;
  int node = blockIdx.x * 32 + nslot;
  int nc = node < NNODES ? node : NNODES - 1;
  const unsigned short* rh = xhi + (size_t)nc * 256;
  const unsigned short* rl = xlo + (size_t)nc * 256;
  float ps[4] = {0.f, 0.f, 0.f, 0.f}, pd[4] = {0.f, 0.f, 0.f, 0.f};
#pragma unroll
  for (int j = 0; j < 8; j++) {
    int k0 = j * 32 + kslot * 4;
    ushort4 h4 = *reinterpret_cast<const ushort4*>(rh + k0);
    ushort4 l4 = *reinterpret_cast<const ushort4*>(rl + k0);
    float xv[4] = {bf2f(h4.x) + bf2f(l4.x), bf2f(h4.y) + bf2f(l4.y),
                   bf2f(h4.z) + bf2f(l4.z), bf2f(h4.w) + bf2f(l4.w)};
#pragma unroll
    for (int m = 0; m < 4; m++) {
      float4 ws = *reinterpret_cast<const float4*>(Was + (k0 + m) * 4);
      float4 wd = *reinterpret_cast<const float4*>(Wad + (k0 + m) * 4);
      ps[0] += xv[m] * ws.x; ps[1] += xv[m] * ws.y; ps[2] += xv[m] * ws.z; ps[3] += xv[m] * ws.w;
      pd[0] += xv[m] * wd.x; pd[1] += xv[m] * wd.y; pd[2] += xv[m] * wd.z; pd[3] += xv[m] * wd.w;
    }
  }
#pragma unroll
  for (int d = 4; d > 0; d >>= 1) {
#pragma unroll
    for (int q = 0; q < 4; q++) {
      ps[q] += __shfl_down(ps[q], d, 64);
      pd[q] += __shfl_down(pd[q], d, 64);
    }
  }
  if (kslot == 0 && node < NNODES) {
    *reinterpret_cast<float4*>(al_s + node * 4) = make_float4(ps[0], ps[1], ps[2], ps[3]);
    *reinterpret_cast<float4*>(al_d + node * 4) = make_float4(pd[0], pd[1], pd[2], pd[3]);
  }
}

// ---------------- gather: 1 wave/node, uint2 loads, packed-f32 fma, byte-offset sS ----------------
// R10 micro-opt: sS stores s<<9 (byte offset of source row) so the unrolled aggregation
// loop does base+off addressing with no per-edge 64-bit multiply chain.
#define ACCP(ux, ev)                                                                     \
  {                                                                                      \
    floatx2 _f01 = {__uint_as_float(ux.x << 16), __uint_as_float(ux.x & 0xffff0000u)};   \
    floatx2 _f23 = {__uint_as_float(ux.y << 16), __uint_as_float(ux.y & 0xffff0000u)};   \
    floatx2 _b0 = {ev.x, ev.x}, _b1 = {ev.y, ev.y}, _b2 = {ev.z, ev.z}, _b3 = {ev.w, ev.w}; \
    acc2[0][0] += _f01 * _b0; acc2[0][1] += _f23 * _b0;                                  \
    acc2[1][0] += _f01 * _b1; acc2[1][1] += _f23 * _b1;                                  \
    acc2[2][0] += _f01 * _b2; acc2[2][1] += _f23 * _b2;                                  \
    acc2[3][0] += _f01 * _b3; acc2[3][1] += _f23 * _b3;                                  \
  }

__global__ __launch_bounds__(256) void gat_gather_kernel(
    const unsigned short* __restrict__ xhi, const float* __restrict__ al_s,
    const float* __restrict__ al_d, const int* __restrict__ row_ptr,
    const int* __restrict__ col_idx,
    unsigned short* __restrict__ aggHi, unsigned short* __restrict__ aggLo) {
  __shared__ int sS[4][64];
  __shared__ float4 sE[4][64];
  int t = threadIdx.x;
  int lane = t & 63, wv = t >> 6;
  int n = blockIdx.x * 4 + wv;
  int start = row_ptr[n], end = row_ptr[n + 1];
  float4 ald4 = *reinterpret_cast<const float4*>(al_d + n * 4);
  float ald[4] = {ald4.x, ald4.y, ald4.z, ald4.w};
  const char* xb = (const char*)(xhi + lane * 4);  // lane's 4-feature slice base

  floatx2 acc2[4][2];
#pragma unroll
  for (int h = 0; h < 4; h++) {
    acc2[h][0] = (floatx2){0.f, 0.f};
    acc2[h][1] = (floatx2){0.f, 0.f};
  }
  float esum[4] = {0.f, 0.f, 0.f, 0.f};

  for (int c = start; c < end; c += 64) {
    int nch = min(64, end - c);
    int soff = 0;
    float ex[4] = {0.f, 0.f, 0.f, 0.f};
    if (lane < nch) {
      int s = col_idx[c + lane];
      soff = s << 9;  // byte offset of row s (256 ushorts = 512 B)
      float4 as4 = *reinterpret_cast<const float4*>(al_s + s * 4);
      float lv[4] = {as4.x + ald[0], as4.y + ald[1], as4.z + ald[2], as4.w + ald[3]};
#pragma unroll
      for (int h = 0; h < 4; h++) {
        float l = lv[h];
        l = (l > 0.f) ? l : 0.2f * l;
        l = fminf(l, 60.f);
        float e = __expf(l);
        ex[h] = e;
        esum[h] += e;
      }
    }
    sS[wv][lane] = soff;
    sE[wv][lane] = make_float4(ex[0], ex[1], ex[2], ex[3]);
    __asm__ __volatile__("" ::: "memory");  // per-wave LDS ops are in-order; pin compiler order
    int i = 0;
    for (; i + 4 <= nch; i += 4) {
      int o0 = sS[wv][i], o1 = sS[wv][i + 1], o2 = sS[wv][i + 2], o3 = sS[wv][i + 3];
      float4 e0 = sE[wv][i], e1 = sE[wv][i + 1], e2 = sE[wv][i + 2], e3 = sE[wv][i + 3];
      uint2 x0 = *reinterpret_cast<const uint2*>(xb + o0);
      uint2 x1 = *reinterpret_cast<const uint2*>(xb + o1);
      uint2 x2 = *reinterpret_cast<const uint2*>(xb + o2);
      uint2 x3 = *reinterpret_cast<const uint2*>(xb + o3);
      ACCP(x0, e0);
      ACCP(x1, e1);
      ACCP(x2, e2);
      ACCP(x3, e3);
    }
    for (; i < nch; i++) {
      int o0 = sS[wv][i];
      float4 e0 = sE[wv][i];
      uint2 x0 = *reinterpret_cast<const uint2*>(xb + o0);
      ACCP(x0, e0);
    }
    __asm__ __volatile__("" ::: "memory");
  }

#pragma unroll
  for (int h = 0; h < 4; h++) {
#pragma unroll
    for (int m = 32; m > 0; m >>= 1) esum[h] += __shfl_xor(esum[h], m, 64);
  }

#pragma unroll
  for (int h = 0; h < 4; h++) {
    float inv = 1.f / (esum[h] + 1e-16f);
    float av[4] = {acc2[h][0].x, acc2[h][0].y, acc2[h][1].x, acc2[h][1].y};
    ushort4 hv, lv;
    unsigned short* hp = (unsigned short*)&hv;
    unsigned short* lp = (unsigned short*)&lv;
#pragma unroll
    for (int j = 0; j < 4; j++) {
      float v = av[j] * inv;
      unsigned u = __float_as_uint(v);
      float r = v - __uint_as_float(u & 0xffff0000u);
      hp[j] = (unsigned short)(u >> 16);
      lp[j] = (unsigned short)(__float_as_uint(r) >> 16);
    }
    size_t o = (size_t)n * 1024 + h * 256 + lane * 4;
    *reinterpret_cast<ushort4*>(aggHi + o) = hv;
    *reinterpret_cast<ushort4*>(aggLo + o) = lv;
  }
}

// ---------------- MFMA GEMM: out[N,256] = xagg[N,1024] @ BT^T + bias, act, split ----------------
#define AHI_OFF 0
#define ALO_OFF 16384
#define BHI_OFF 32768
#define BLO_OFF 49152

__global__ __launch_bounds__(256, 1) void gemm_out_kernel(
    const unsigned short* __restrict__ aggHi, const unsigned short* __restrict__ aggLo,
    const unsigned short* __restrict__ btHi, const unsigned short* __restrict__ btLo,
    const float* __restrict__ bias, float* __restrict__ outF,
    unsigned short* __restrict__ outHi, unsigned short* __restrict__ outLo, int act_tanh) {
  __shared__ __align__(16) char lds[131072];
  int t = threadIdx.x;
  int lane = t & 63, wv = t >> 6;
  int quad = lane >> 4, lr = lane & 15;
  int row0 = blockIdx.y * 128;
  int col0 = blockIdx.x * 128;
  int wm = (wv & 1) * 64, wn = (wv >> 1) * 64;

  floatx4 acc[4][4];
#pragma unroll
  for (int i = 0; i < 4; i++)
#pragma unroll
    for (int j = 0; j < 4; j++) acc[i][j] = (floatx4){0.f, 0.f, 0.f, 0.f};

  auto stage = [&](int ks, int bufbase) {
#pragma unroll
    for (int mat = 0; mat < 4; mat++) {
      const unsigned short* src = (mat == 0) ? aggHi : (mat == 1) ? aggLo : (mat == 2) ? btHi : btLo;
      int rowbase = (mat < 2) ? row0 : col0;
      int maxrow = (mat < 2) ? (NNODES - 1) : 255;
      int ldsoff = bufbase + mat * 16384;
#pragma unroll
      for (int it = 0; it < 4; it++) {
        int lin = ((wv * 4 + it) << 10) + lane * 16;
        int R = lin >> 7;
        int c = (lin >> 4) & 7;
        int g = c ^ (R & 7);
        int gr = rowbase + R;
        if (gr > maxrow) gr = maxrow;
        const char* gp = (const char*)src + (size_t)gr * 2048 + ks * 128 + g * 16;
        __builtin_amdgcn_global_load_lds(
            (const __attribute__((address_space(1))) void*)gp,
            (__attribute__((address_space(3))) void*)(lds + ldsoff + lin), 16, 0, 0);
      }
    }
  };

  stage(0, 0);
  asm volatile("s_waitcnt vmcnt(0)" ::: "memory");
  __builtin_amdgcn_s_barrier();
  asm volatile("" ::: "memory");

  int cur = 0;
  for (int ks = 0; ks < 16; ks++) {
    if (ks < 15) stage(ks + 1, (cur ^ 1) * 65536);

    int base = cur * 65536;
#pragma unroll
    for (int ksub = 0; ksub < 2; ksub++) {
      int g = ksub * 4 + quad;
      bf16x8 ah[4], al_[4], bh[4], bl[4];
#pragma unroll
      for (int mi = 0; mi < 4; mi++) {
        int m = wm + mi * 16 + lr;
        int off = m * 128 + ((g ^ (m & 7)) << 4);
        ah[mi] = *(const bf16x8*)(lds + base + AHI_OFF + off);
        al_[mi] = *(const bf16x8*)(lds + base + ALO_OFF + off);
      }
#pragma unroll
      for (int ni = 0; ni < 4; ni++) {
        int n = wn + ni * 16 + lr;
        int off = n * 128 + ((g ^ (n & 7)) << 4);
        bh[ni] = *(const bf16x8*)(lds + base + BHI_OFF + off);
        bl[ni] = *(const bf16x8*)(lds + base + BLO_OFF + off);
      }
#pragma unroll
      for (int mi = 0; mi < 4; mi++)
#pragma unroll
        for (int ni = 0; ni < 4; ni++) {
          acc[mi][ni] = __builtin_amdgcn_mfma_f32_16x16x32_bf16(ah[mi], bh[ni], acc[mi][ni], 0, 0, 0);
          acc[mi][ni] = __builtin_amdgcn_mfma_f32_16x16x32_bf16(ah[mi], bl[ni], acc[mi][ni], 0, 0, 0);
          acc[mi][ni] = __builtin_amdgcn_mfma_f32_16x16x32_bf16(al_[mi], bh[ni], acc[mi][ni], 0, 0, 0);
        }
    }

    asm volatile("s_waitcnt vmcnt(0)" ::: "memory");
    __builtin_amdgcn_s_barrier();
    asm volatile("" ::: "memory");
    cur ^= 1;
  }

#pragma unroll
  for (int mi = 0; mi < 4; mi++) {
#pragma unroll
    for (int ni = 0; ni < 4; ni++) {
      int col = col0 + wn + ni * 16 + lr;
      float bv = bias[col];
#pragma unroll
      for (int r = 0; r < 4; r++) {
        int row = row0 + wm + mi * 16 + quad * 4 + r;
        if (row < NNODES) {
          float v = acc[mi][ni][r] + bv;
          v = act_tanh ? tanhf(v) : fmaxf(v, 0.f);
          size_t o = (size_t)row * 256 + col;
          if (outF) outF[o] = v;
          unsigned u = __float_as_uint(v);
          float rr = v - __uint_as_float(u & 0xffff0000u);
          outHi[o] = (unsigned short)(u >> 16);
          outLo[o] = (unsigned short)(__float_as_uint(rr) >> 16);
        }
      }
    }
  }
}

// ---------------- adj = sigmoid(Z @ Z^T), triangular grid, full-line writes (no RFO) ----------------
__global__ __launch_bounds__(256, 2) void zzt_mfma_kernel(
    const unsigned short* __restrict__ zhi, const unsigned short* __restrict__ zlo,
    float* __restrict__ out) {
  __shared__ __align__(16) char lds[65536];
  int t = threadIdx.x;
  int lane = t & 63, wv = t >> 6;
  int quad = lane >> 4, lr = lane & 15;

  int p = blockIdx.x;
  int bi = (int)((159.0f - sqrtf(159.0f * 159.0f - 8.0f * (float)p)) * 0.5f);
  if (bi < 0) bi = 0;
  if (bi > NT - 1) bi = NT - 1;
  while (bi * NT - bi * (bi - 1) / 2 > p) bi--;
  while ((bi + 1) * NT - (bi + 1) * bi / 2 <= p) bi++;
  int bj = bi + (p - (bi * NT - bi * (bi - 1) / 2));
  int row0 = bi * 128;
  int col0 = bj * 128;
  int wm = (wv & 1) * 64, wn = (wv >> 1) * 64;

  floatx4 acc[4][4];
#pragma unroll
  for (int i = 0; i < 4; i++)
#pragma unroll
    for (int j = 0; j < 4; j++) acc[i][j] = (floatx4){0.f, 0.f, 0.f, 0.f};

  for (int ks = 0; ks < 4; ks++) {
#pragma unroll
    for (int mat = 0; mat < 4; mat++) {
      const unsigned short* src = (mat == 0 || mat == 2) ? zhi : zlo;
      int rowbase = (mat < 2) ? row0 : col0;
      int ldsoff = mat * 16384;
#pragma unroll
      for (int it = 0; it < 4; it++) {
        int lin = ((wv * 4 + it) << 10) + lane * 16;
        int R = lin >> 7;
        int c = (lin >> 4) & 7;
        int g = c ^ (R & 7);
        int gr = rowbase + R;
        if (gr > NNODES - 1) gr = NNODES - 1;
        const char* gp = (const char*)src + (size_t)gr * 512 + ks * 128 + g * 16;
        __builtin_amdgcn_global_load_lds(
            (const __attribute__((address_space(1))) void*)gp,
            (__attribute__((address_space(3))) void*)(lds + ldsoff + lin), 16, 0, 0);
      }
    }
    __syncthreads();

#pragma unroll
    for (int ksub = 0; ksub < 2; ksub++) {
      int g = ksub * 4 + quad;
      bf16x8 ah[4], al_[4], bh[4], bl[4];
#pragma unroll
      for (int mi = 0; mi < 4; mi++) {
        int m = wm + mi * 16 + lr;
        int off = m * 128 + ((g ^ (m & 7)) << 4);
        ah[mi] = *(const bf16x8*)(lds + AHI_OFF + off);
        al_[mi] = *(const bf16x8*)(lds + ALO_OFF + off);
      }
#pragma unroll
      for (int ni = 0; ni < 4; ni++) {
        int n = wn + ni * 16 + lr;
        int off = n * 128 + ((g ^ (n & 7)) << 4);
        bh[ni] = *(const bf16x8*)(lds + BHI_OFF + off);
        bl[ni] = *(const bf16x8*)(lds + BLO_OFF + off);
      }
#pragma unroll
      for (int mi = 0; mi < 4; mi++)
#pragma unroll
        for (int ni = 0; ni < 4; ni++) {
          acc[mi][ni] = __builtin_amdgcn_mfma_f32_16x16x32_bf16(ah[mi], bh[ni], acc[mi][ni], 0, 0, 0);
          acc[mi][ni] = __builtin_amdgcn_mfma_f32_16x16x32_bf16(ah[mi], bl[ni], acc[mi][ni], 0, 0, 0);
          acc[mi][ni] = __builtin_amdgcn_mfma_f32_16x16x32_bf16(al_[mi], bh[ni], acc[mi][ni], 0, 0, 0);
        }
    }
    __syncthreads();
  }

  bool diag = (bi == bj);
  float4* ltile = (float4*)lds;
  const float* ltf = (const float*)lds;

#pragma unroll
  for (int mi = 0; mi < 4; mi++) {
#pragma unroll
    for (int ni = 0; ni < 4; ni++) {
      int cl = wn + ni * 16 + lr;
      float4 sv;
      sv.x = 1.f / (1.f + __expf(-acc[mi][ni][0]));
      sv.y = 1.f / (1.f + __expf(-acc[mi][ni][1]));
      sv.z = 1.f / (1.f + __expf(-acc[mi][ni][2]));
      sv.w = 1.f / (1.f + __expf(-acc[mi][ni][3]));
      int rl0 = wm + mi * 16 + quad * 4;
      int rq = rl0 >> 2;
      ltile[cl * 32 + ((rq + cl) & 31)] = sv;
    }
  }
  __syncthreads();

  {
    int hw = t >> 5, l = t & 31;
    bool colok = (col0 + 4 * l + 4 <= NNODES);
#pragma unroll
    for (int it = 0; it < 16; it++) {
      int r = it * 8 + hw;
      int row = row0 + r;
      if (colok && row < NNODES) {
        int rq = r >> 2, comp = r & 3;
        float4 v;
#pragma unroll
        for (int j = 0; j < 4; j++) {
          int cc = 4 * l + j;
          ((float*)&v)[j] = ltf[(cc * 32 + ((rq + cc) & 31)) * 4 + comp];
        }
        *reinterpret_cast<float4*>(&out[(size_t)row * NNODES + col0 + 4 * l]) = v;
      }
    }
  }

  if (!diag) {
#pragma unroll
    for (int it = 0; it < 16; it++) {
      int cl = wv * 32 + it * 2 + (lane >> 5);
      int rq = lane & 31;
      int col = col0 + cl;
      if (col < NNODES) {
        float4 v = ltile[cl * 32 + ((rq + cl) & 31)];
        *reinterpret_cast<float4*>(&out[(size_t)col * NNODES + row0 + 4 * rq]) = v;
      }
    }
  }
}

extern "C" void kernel_launch(void* const* d_in, const int* in_sizes, int n_in,
                              void* d_out, int out_size, void* d_ws, size_t ws_size,
                              hipStream_t stream) {
  const float* x = (const float*)d_in[0];
  const int* ei = (const int*)d_in[1];
  const float* W[4]  = {(const float*)d_in[2], (const float*)d_in[6], (const float*)d_in[10], (const float*)d_in[14]};
  const float* as[4] = {(const float*)d_in[3], (const float*)d_in[7], (const float*)d_in[11], (const float*)d_in[15]};
  const float* ad[4] = {(const float*)d_in[4], (const float*)d_in[8], (const float*)d_in[12], (const float*)d_in[16]};
  const float* bs[4] = {(const float*)d_in[5], (const float*)d_in[9], (const float*)d_in[13], (const float*)d_in[17]};

  char* ws = (char*)d_ws;
  size_t off = 0;
  auto alloc = [&](size_t bytes) -> void* {
    void* p = ws + off;
    off = (off + bytes + 255) & ~(size_t)255;
    return p;
  };
  unsigned short* aggHi = (unsigned short*)alloc(sizeof(unsigned short) * (size_t)NNODES * 1024);
  unsigned short* aggLo = (unsigned short*)alloc(sizeof(unsigned short) * (size_t)NNODES * 1024);
  unsigned short* shi   = (unsigned short*)alloc(sizeof(unsigned short) * (size_t)NNODES * FDIM);
  unsigned short* slo   = (unsigned short*)alloc(sizeof(unsigned short) * (size_t)NNODES * FDIM);
  unsigned short* btHi  = (unsigned short*)alloc(sizeof(unsigned short) * 4 * 256 * 1024);
  unsigned short* btLo  = (unsigned short*)alloc(sizeof(unsigned short) * 4 * 256 * 1024);
  float* al_s  = (float*)alloc(sizeof(float) * NNODES * 4);
  float* al_d  = (float*)alloc(sizeof(float) * NNODES * 4);
  float* Was   = (float*)alloc(sizeof(float) * 4 * 256 * 4);
  float* Wad   = (float*)alloc(sizeof(float) * 4 * 256 * 4);
  int* counts  = (int*)alloc(sizeof(int) * NNODES);
  int* row_ptr = (int*)alloc(sizeof(int) * (NNODES + 1));
  int* fill    = (int*)alloc(sizeof(int) * NNODES);
  int* col_idx = (int*)alloc(sizeof(int) * ETOT);

  hipMemsetAsync(counts, 0, sizeof(int) * NNODES, stream);
  preproc_kernel<<<13338, 256, 0, stream>>>(x, ei, W[0], W[1], W[2], W[3],
                                            as[0], as[1], as[2], as[3],
                                            ad[0], ad[1], ad[2], ad[3],
                                            shi, slo, btHi, btLo, Was, Wad, counts);
  scan_kernel<<<1, 256, 0, stream>>>(counts, row_ptr, fill);
  scatter_kernel<<<(ETOT + 255) / 256, 256, 0, stream>>>(ei, fill, col_idx);

  float* z = (float*)d_out + (size_t)NNODES * NNODES;
  for (int l = 0; l < 4; l++) {
    al_kernel<<<(NNODES + 31) / 32, 256, 0, stream>>>(shi, slo, Was + l * 1024, Wad + l * 1024,
                                                      al_s, al_d);
    gat_gather_kernel<<<NNODES / 4, 256, 0, stream>>>(shi, al_s, al_d, row_ptr, col_idx,
                                                      aggHi, aggLo);
    float* outF = (l == 3) ? z : (float*)nullptr;
    gemm_out_kernel<<<dim3(2, 79), 256, 0, stream>>>(aggHi, aggLo,
                                                     btHi + (size_t)l * 262144,
                                                     btLo + (size_t)l * 262144, bs[l],
                                                     outF, shi, slo, l == 3 ? 1 : 0);
  }
  zzt_mfma_kernel<<<NT * (NT + 1) / 2, 256, 0, stream>>>(shi, slo, (float*)d_out);
}